// Round 11
// baseline (25.407 us; speedup 1.0000x reference)
//
#include <hip/hip_runtime.h>

#define NPTS 524288
#define HID 100
#define BLK 256
// PPT=2 point-pair packed fp32 (v_pk_fma_f32), table in d_ws read via the
// SCALAR path: pointer made provably wave-uniform with readfirstlane so the
// per-j float4 loads select s_load_dwordx4 (SMEM) — removes the ~10us/CU
// LDS-pipe term (125 broadcast ds_read_b128/thread @ ~12cy) that R10 paid.
// Remaining pipes per SIMD: pk-VALU ~6400 cy (2.7us) | trans ~6400-12800 cy.

typedef float v2f __attribute__((ext_vector_type(2)));

#if __has_builtin(__builtin_elementwise_fma)
#define VFMA(a, b, c) __builtin_elementwise_fma((a), (b), (c))
#else
#define VFMA(a, b, c) ((a) * (b) + (c))
#endif

// tabA[j] = { w1x*2log2e, w1y*2log2e, b1*2log2e, ku }   (1600 B)
// tabK4[j4] = 4 kv values                                (400 B)
// ku = 2*W2*w1y*(w1x - w1y)   (u = Hxy - Hyy accumulates s*ku)
// kv = 2*W2*w1x*(w1y - w1x)   (v = Hxy - Hxx accumulates s*kv)
__global__ void kDivFree_prep(const float* __restrict__ W1,
                              const float* __restrict__ b1,
                              const float* __restrict__ W2,
                              float4* __restrict__ tabA,
                              float*  __restrict__ tabK) {
    int j = threadIdx.x;
    if (j < HID) {
        const float C = 2.8853900817779268f;  // 2*log2(e)
        float w1x = W1[j], w1y = W1[HID + j], w2 = W2[j];
        tabA[j] = make_float4(w1x * C, w1y * C, b1[j] * C,
                              2.0f * w2 * w1y * (w1x - w1y));
        tabK[j] = 2.0f * w2 * w1x * (w1y - w1x);
    }
}

__device__ __forceinline__ const float4* uniform_ptr(const float4* p) {
    uint64_t u = (uint64_t)p;
    uint32_t lo = __builtin_amdgcn_readfirstlane((uint32_t)u);
    uint32_t hi = __builtin_amdgcn_readfirstlane((uint32_t)(u >> 32));
    return (const float4*)(((uint64_t)hi << 32) | (uint64_t)lo);
}

// s(a) = h^3 - h, h = tanh(a):  t = e^{2a}, r = 1/(1+t), h = 1-2r.
__global__ void __launch_bounds__(BLK)
kDivFree_main(const float2* __restrict__ xy,
              const float4* __restrict__ tabA_,
              const float4* __restrict__ tabK_,
              float2* __restrict__ out) {
    const float4* tabA = uniform_ptr(tabA_);
    const float4* tabK = uniform_ptr(tabK_);

    int base = blockIdx.x * (BLK * 2) + threadIdx.x;
    float2 p0 = xy[base];
    float2 p1 = xy[base + BLK];
    v2f px = {p0.x, p1.x};
    v2f py = {p0.y, p1.y};
    v2f u = {0.0f, 0.0f};
    v2f v = {0.0f, 0.0f};
    const v2f one = 1.0f, mtwo = -2.0f, mone = -1.0f;

#pragma unroll 5
    for (int j4 = 0; j4 < HID / 4; ++j4) {
        float4 K = tabK[j4];
        float kva[4] = {K.x, K.y, K.z, K.w};
#pragma unroll
        for (int jj = 0; jj < 4; ++jj) {
            float4 A = tabA[j4 * 4 + jj];
            v2f ax = A.x, ay = A.y, az = A.z, ku = A.w, kv = kva[jj];
            v2f y = VFMA(px, ax, VFMA(py, ay, az));   // 2log2e*(x w1x + y w1y + b)
            v2f e;
            e.x = __builtin_amdgcn_exp2f(y.x);        // e^{2a}
            e.y = __builtin_amdgcn_exp2f(y.y);
            v2f d = e + one;
            v2f r;
            r.x = __builtin_amdgcn_rcpf(d.x);         // 1/(1+e^{2a})
            r.y = __builtin_amdgcn_rcpf(d.y);
            v2f h  = VFMA(mtwo, r, one);              // tanh(a)
            v2f hm = VFMA(h, h, mone);                // h^2 - 1
            v2f s  = h * hm;                          // h^3 - h
            u = VFMA(s, ku, u);
            v = VFMA(s, kv, v);
        }
    }

    out[base]       = make_float2(u.x, v.x);
    out[base + BLK] = make_float2(u.y, v.y);
}

extern "C" void kernel_launch(void* const* d_in, const int* in_sizes, int n_in,
                              void* d_out, int out_size, void* d_ws, size_t ws_size,
                              hipStream_t stream) {
    // inputs: 0=f (unused), 1=xy, 2=W1, 3=b1, 4=W2, 5=b2 (unused by Hessian)
    const float* xy = (const float*)d_in[1];
    const float* W1 = (const float*)d_in[2];
    const float* b1 = (const float*)d_in[3];
    const float* W2 = (const float*)d_in[4];
    float4* tabA = (float4*)d_ws;                 // 1600 B
    float*  tabK = (float*)((char*)d_ws + 1600);  // 400 B, 16B-aligned

    kDivFree_prep<<<1, 128, 0, stream>>>(W1, b1, W2, tabA, tabK);
    kDivFree_main<<<NPTS / (BLK * 2), BLK, 0, stream>>>(
        (const float2*)xy, tabA, (const float4*)tabK, (float2*)d_out);
}

// Round 12
// 20.812 us; speedup vs baseline: 1.2208x; 1.2208x over previous
//
#include <hip/hip_runtime.h>

#define NPTS 524288
#define HID 100
#define BLK 256
#define PPT 4   // 2 packed v2f point-pairs per thread
// Fused kernel, packed fp32 math (v_pk_fma_f32). Table shrunk to ONE float4
// per j: {cx, cy, cz, g'} with cx=C*w1x, cy=C*w1y, cz=C*b1, C=2log2(e),
// g' = 2*W2*(w1x-w1y)/C  =>  ku = g'*cy, kv = -g'*cx.
// Per-CU LDS traffic halves vs R10 (8 waves x 100 ds_read_b128 instead of
// 16 x 125): tests whether the ~14us unexplained term is the LDS pipe.
// Per pair-j issue: 10 pk-VALU + 4 trans ~= 36 cy; 2 indep chains/wave.

typedef float v2f __attribute__((ext_vector_type(2)));

#if __has_builtin(__builtin_elementwise_fma)
#define VFMA(a, b, c) __builtin_elementwise_fma((a), (b), (c))
#else
#define VFMA(a, b, c) ((a) * (b) + (c))
#endif

__global__ void __launch_bounds__(BLK)
kDivFree_main(const float2* __restrict__ xy,
              const float* __restrict__ W1,
              const float* __restrict__ b1,
              const float* __restrict__ W2,
              float2* __restrict__ out) {
    __shared__ float4 sA[HID];   // {cx, cy, cz, g'}  1600 B

    int t = threadIdx.x;
    if (t < HID) {
        const float C = 2.8853900817779268f;   // 2*log2(e)
        float w1x = W1[t], w1y = W1[HID + t], w2 = W2[t];
        sA[t] = make_float4(w1x * C, w1y * C, b1[t] * C,
                            (2.0f / C) * w2 * (w1x - w1y));
    }
    __syncthreads();

    int base = blockIdx.x * (BLK * PPT) + threadIdx.x;
    float2 q0 = xy[base];
    float2 q1 = xy[base + BLK];
    float2 q2 = xy[base + 2 * BLK];
    float2 q3 = xy[base + 3 * BLK];
    v2f pxA = {q0.x, q1.x}, pyA = {q0.y, q1.y};
    v2f pxB = {q2.x, q3.x}, pyB = {q2.y, q3.y};
    v2f uA = 0.0f, vA = 0.0f, uB = 0.0f, vB = 0.0f;
    const v2f one = 1.0f, mtwo = -2.0f, mone = -1.0f;

#pragma unroll 4
    for (int j = 0; j < HID; ++j) {
        float4 A = sA[j];
        v2f ax = A.x, ay = A.y, az = A.z, g = A.w;
        {   // pair A
            v2f y = VFMA(pxA, ax, VFMA(pyA, ay, az));
            v2f e; e.x = __builtin_amdgcn_exp2f(y.x);
                   e.y = __builtin_amdgcn_exp2f(y.y);
            v2f d = e + one;
            v2f r; r.x = __builtin_amdgcn_rcpf(d.x);
                   r.y = __builtin_amdgcn_rcpf(d.y);
            v2f h  = VFMA(mtwo, r, one);
            v2f hm = VFMA(h, h, mone);
            v2f m  = (h * hm) * g;          // s * g'
            uA = VFMA(m, ay, uA);           // += s*ku, ku = g'*cy
            vA = VFMA(m, -ax, vA);          // += s*kv, kv = -g'*cx
        }
        {   // pair B
            v2f y = VFMA(pxB, ax, VFMA(pyB, ay, az));
            v2f e; e.x = __builtin_amdgcn_exp2f(y.x);
                   e.y = __builtin_amdgcn_exp2f(y.y);
            v2f d = e + one;
            v2f r; r.x = __builtin_amdgcn_rcpf(d.x);
                   r.y = __builtin_amdgcn_rcpf(d.y);
            v2f h  = VFMA(mtwo, r, one);
            v2f hm = VFMA(h, h, mone);
            v2f m  = (h * hm) * g;
            uB = VFMA(m, ay, uB);
            vB = VFMA(m, -ax, vB);
        }
    }

    out[base]           = make_float2(uA.x, vA.x);
    out[base + BLK]     = make_float2(uA.y, vA.y);
    out[base + 2 * BLK] = make_float2(uB.x, vB.x);
    out[base + 3 * BLK] = make_float2(uB.y, vB.y);
}

extern "C" void kernel_launch(void* const* d_in, const int* in_sizes, int n_in,
                              void* d_out, int out_size, void* d_ws, size_t ws_size,
                              hipStream_t stream) {
    // inputs: 0=f (unused), 1=xy, 2=W1, 3=b1, 4=W2, 5=b2 (unused by Hessian)
    const float* xy = (const float*)d_in[1];
    const float* W1 = (const float*)d_in[2];
    const float* b1 = (const float*)d_in[3];
    const float* W2 = (const float*)d_in[4];

    kDivFree_main<<<NPTS / (BLK * PPT), BLK, 0, stream>>>(
        (const float2*)xy, W1, b1, W2, (float2*)d_out);
}